// Round 2
// baseline (98.186 us; speedup 1.0000x reference)
//
#include <hip/hip_runtime.h>
#include <math.h>

#define BATCH 256
#define DIMZ  64
#define NSAMP 32
#define JB    8   // j values per block (8 j x 32 s = 256 threads)

// ws layout (floats): A[DIMZ*BATCH] | R[DIMZ*BATCH] | M[DIMZ*BATCH]
//   t2(i,d;z) = A - (R*(z - M))^2   (log2-domain Gaussian log-density)
// Needs 3*64*256*4 = 196 KiB of ws.

__global__ __launch_bounds__(256) void lpo_build_tables(
    const float* __restrict__ post_mean,
    const float* __restrict__ post_logvar,
    float* __restrict__ ws)
{
    constexpr float LOG_2PI = 1.8378770664093453f;
    constexpr float VAR_EPS = 1e-4f;
    constexpr float LOG2E   = 1.4426950408889634f;

    const int d = blockIdx.x;    // 0..63
    const int i = threadIdx.x;   // 0..255
    const float m   = post_mean[i * DIMZ + d];
    const float lv  = post_logvar[i * DIMZ + d];
    const float den = 2.0f * __expf(lv) + VAR_EPS;
    const float A   = LOG2E * (-0.5f * LOG_2PI - 0.5f * lv);
    const float r   = sqrtf(LOG2E / den);
    ws[d * BATCH + i]                     = A;
    ws[DIMZ * BATCH + d * BATCH + i]      = r;
    ws[2 * DIMZ * BATCH + d * BATCH + i]  = m;
}

__global__ __launch_bounds__(256) void lpo_kl_kernel(
    const float* __restrict__ prior_mean,
    const float* __restrict__ prior_logvar,
    const float* __restrict__ post_mean,
    const float* __restrict__ post_logvar,
    const float* __restrict__ eps,
    const float* __restrict__ tab,   // == ws, read-only here (s_load path)
    float* __restrict__ out)
{
    constexpr float LOG_2PI = 1.8378770664093453f;
    constexpr float VAR_EPS = 1e-4f;
    constexpr float LN2     = 0.6931471805599453f;
    constexpr float LOG_B   = 5.545177444479562f;   // ln(256)

    __shared__ float wred[4];

    const int tid = threadIdx.x;
    const int d   = blockIdx.x & (DIMZ - 1);
    const int j0  = (blockIdx.x >> 6) * JB;

    const int s  = tid & (NSAMP - 1);
    const int jj = tid >> 5;
    const int j  = j0 + jj;

    // reparameterized sample z_{j,d,s} straight from global (cheap, once)
    const float pmj = post_mean[j * DIMZ + d];
    const float plj = post_logvar[j * DIMZ + d];
    const float z   = pmj + eps[(j * DIMZ + d) * NSAMP + s] * __expf(0.5f * plj);

    // uniform-address table pointers -> scalar loads (s_load_dwordx4)
    const float4* __restrict__ At = (const float4*)(tab + (size_t)d * BATCH);
    const float4* __restrict__ Rt = (const float4*)(tab + (size_t)DIMZ * BATCH + (size_t)d * BATCH);
    const float4* __restrict__ Mt = (const float4*)(tab + (size_t)2 * DIMZ * BATCH + (size_t)d * BATCH);

    // sum_i 2^{t2_i}; no max-stabilization needed:
    //   t2 <= ~2.2 (no overflow); diagonal i=j term has t2 >= ~-30 (no total underflow)
    float sum0 = 0.f, sum1 = 0.f, sum2 = 0.f, sum3 = 0.f;
    #pragma unroll 4
    for (int ii = 0; ii < BATCH / 4; ++ii) {
        const float4 Av = At[ii];
        const float4 Rv = Rt[ii];
        const float4 Mv = Mt[ii];
        float u0 = (z - Mv.x) * Rv.x; sum0 += __builtin_amdgcn_exp2f(fmaf(-u0, u0, Av.x));
        float u1 = (z - Mv.y) * Rv.y; sum1 += __builtin_amdgcn_exp2f(fmaf(-u1, u1, Av.y));
        float u2 = (z - Mv.z) * Rv.z; sum2 += __builtin_amdgcn_exp2f(fmaf(-u2, u2, Av.z));
        float u3 = (z - Mv.w) * Rv.w; sum3 += __builtin_amdgcn_exp2f(fmaf(-u3, u3, Av.w));
    }
    const float sum = (sum0 + sum1) + (sum2 + sum3);

    // prior log-density at z (natural log, once per output)
    const float pm   = prior_mean[j * DIMZ + d];
    const float plv  = prior_logvar[j * DIMZ + d];
    const float pden = 2.0f * __expf(plv) + VAR_EPS;
    const float dz   = z - pm;
    const float logp_prior = -0.5f * LOG_2PI - 0.5f * plv - dz * dz / pden;

    // logsumexp_nat = ln2*log2(sum) - ln(B); gap; mean over (j,s), sum over d
    const float lse_nat = LN2 * __builtin_amdgcn_logf(sum) - LOG_B;
    float contrib = (lse_nat - logp_prior) * (1.0f / (BATCH * NSAMP));

    // wave reduce (width 64) -> cross-wave via LDS -> one atomic per block
    for (int off = 32; off > 0; off >>= 1)
        contrib += __shfl_down(contrib, off);
    if ((tid & 63) == 0) wred[tid >> 6] = contrib;
    __syncthreads();
    if (tid == 0)
        atomicAdd(out, (wred[0] + wred[1]) + (wred[2] + wred[3]));
}

extern "C" void kernel_launch(void* const* d_in, const int* in_sizes, int n_in,
                              void* d_out, int out_size, void* d_ws, size_t ws_size,
                              hipStream_t stream) {
    const float* prior_mean   = (const float*)d_in[0];
    const float* prior_logvar = (const float*)d_in[1];
    const float* post_mean    = (const float*)d_in[2];
    const float* post_logvar  = (const float*)d_in[3];
    const float* eps          = (const float*)d_in[4];
    float* out = (float*)d_out;
    float* ws  = (float*)d_ws;

    // harness poisons d_out with 0xAA before every timed launch
    hipMemsetAsync(out, 0, sizeof(float), stream);

    lpo_build_tables<<<dim3(DIMZ), dim3(256), 0, stream>>>(post_mean, post_logvar, ws);

    lpo_kl_kernel<<<dim3((BATCH / JB) * DIMZ), dim3(256), 0, stream>>>(
        prior_mean, prior_logvar, post_mean, post_logvar, eps, ws, out);
}

// Round 3
// 95.935 us; speedup vs baseline: 1.0235x; 1.0235x over previous
//
#include <hip/hip_runtime.h>
#include <math.h>

#define BATCH 256
#define DIMZ  64
#define NSAMP 32
#define JB    8   // j values per block (8 j x 32 s = 256 threads)

typedef float v2f __attribute__((ext_vector_type(2)));

__global__ __launch_bounds__(256) void lpo_kl_kernel(
    const float* __restrict__ prior_mean,
    const float* __restrict__ prior_logvar,
    const float* __restrict__ post_mean,
    const float* __restrict__ post_logvar,
    const float* __restrict__ eps,
    float* __restrict__ out)
{
    constexpr float LOG_2PI = 1.8378770664093453f;
    constexpr float VAR_EPS = 1e-4f;
    constexpr float LOG2E   = 1.4426950408889634f;
    constexpr float LN2     = 0.6931471805599453f;
    constexpr float LOG_B   = 5.545177444479562f;   // ln(256)

    // SoA tables: log2-domain density as a quadratic in z:
    //   t2(i) = a_i + b_i*z - c_i*z^2;  store cn = -c so both steps are FMA.
    __shared__ __align__(16) float a_s[BATCH];
    __shared__ __align__(16) float b_s[BATCH];
    __shared__ __align__(16) float cn_s[BATCH];
    __shared__ float sg_s[BATCH];    // exp(0.5*logvar) for sample construction
    __shared__ float m_s[BATCH];     // post_mean (for z)
    __shared__ float wred[4];

    const int tid = threadIdx.x;
    const int d   = blockIdx.x & (DIMZ - 1);
    const int j0  = (blockIdx.x >> 6) * JB;

    // Build per-d table: one entry per batch index i (one thread each).
    {
        const int i = tid;
        const float m   = post_mean[i * DIMZ + d];
        const float lv  = post_logvar[i * DIMZ + d];
        const float den = 2.0f * __expf(lv) + VAR_EPS;
        const float V   = LOG2E / den;                       // curvature
        const float A   = LOG2E * (-0.5f * LOG_2PI - 0.5f * lv);
        a_s[i]  = fmaf(-V * m, m, A);    // A - V m^2
        b_s[i]  = 2.0f * V * m;
        cn_s[i] = -V;
        m_s[i]  = m;
        sg_s[i] = __expf(0.5f * lv);
    }
    __syncthreads();

    const int s  = tid & (NSAMP - 1);
    const int jj = tid >> 5;
    const int j  = j0 + jj;

    // reparameterized sample z_{j,d,s}
    const float z  = m_s[j] + eps[(j * DIMZ + d) * NSAMP + s] * sg_s[j];
    const v2f   z2 = {z, z};

    // sum_i 2^{t2_i}; no max-stabilization needed:
    //   t2 <= ~2.2 (no overflow); diagonal i=j term keeps sum >= ~2^-30
    v2f acc0 = {0.f, 0.f}, acc1 = {0.f, 0.f}, acc2 = {0.f, 0.f}, acc3 = {0.f, 0.f};

#define PAIR(ax, ay, bx, by, cx, cy, ACC)                                   \
    {                                                                       \
        v2f av = {ax, ay}, bv = {bx, by}, cv = {cx, cy};                    \
        v2f t1 = __builtin_elementwise_fma(cv, z2, bv);                     \
        v2f t2 = __builtin_elementwise_fma(t1, z2, av);                     \
        v2f e  = {__builtin_amdgcn_exp2f(t2.x), __builtin_amdgcn_exp2f(t2.y)}; \
        ACC += e;                                                           \
    }

    #pragma unroll 2
    for (int i = 0; i < BATCH; i += 8) {
        const float4 av0 = *(const float4*)(a_s + i);
        const float4 bv0 = *(const float4*)(b_s + i);
        const float4 cv0 = *(const float4*)(cn_s + i);
        const float4 av1 = *(const float4*)(a_s + i + 4);
        const float4 bv1 = *(const float4*)(b_s + i + 4);
        const float4 cv1 = *(const float4*)(cn_s + i + 4);
        PAIR(av0.x, av0.y, bv0.x, bv0.y, cv0.x, cv0.y, acc0);
        PAIR(av0.z, av0.w, bv0.z, bv0.w, cv0.z, cv0.w, acc1);
        PAIR(av1.x, av1.y, bv1.x, bv1.y, cv1.x, cv1.y, acc2);
        PAIR(av1.z, av1.w, bv1.z, bv1.w, cv1.z, cv1.w, acc3);
    }
#undef PAIR

    const v2f accp = (acc0 + acc1) + (acc2 + acc3);
    const float sum = accp.x + accp.y;

    // prior log-density at z (natural log, once per output)
    const float pm   = prior_mean[j * DIMZ + d];
    const float plv  = prior_logvar[j * DIMZ + d];
    const float pden = 2.0f * __expf(plv) + VAR_EPS;
    const float dz   = z - pm;
    const float logp_prior = -0.5f * LOG_2PI - 0.5f * plv - dz * dz / pden;

    // logsumexp_nat = ln2*log2(sum) - ln(B); gap; mean over (j,s), sum over d
    const float lse_nat = LN2 * __builtin_amdgcn_logf(sum) - LOG_B;
    float contrib = (lse_nat - logp_prior) * (1.0f / (BATCH * NSAMP));

    // wave reduce (width 64) -> cross-wave via LDS -> one atomic per block
    for (int off = 32; off > 0; off >>= 1)
        contrib += __shfl_down(contrib, off);
    if ((tid & 63) == 0) wred[tid >> 6] = contrib;
    __syncthreads();
    if (tid == 0)
        atomicAdd(out, (wred[0] + wred[1]) + (wred[2] + wred[3]));
}

extern "C" void kernel_launch(void* const* d_in, const int* in_sizes, int n_in,
                              void* d_out, int out_size, void* d_ws, size_t ws_size,
                              hipStream_t stream) {
    const float* prior_mean   = (const float*)d_in[0];
    const float* prior_logvar = (const float*)d_in[1];
    const float* post_mean    = (const float*)d_in[2];
    const float* post_logvar  = (const float*)d_in[3];
    const float* eps          = (const float*)d_in[4];
    float* out = (float*)d_out;

    // harness poisons d_out with 0xAA before every timed launch
    hipMemsetAsync(out, 0, sizeof(float), stream);

    lpo_kl_kernel<<<dim3((BATCH / JB) * DIMZ), dim3(256), 0, stream>>>(
        prior_mean, prior_logvar, post_mean, post_logvar, eps, out);
}